// Round 11
// baseline (133.031 us; speedup 1.0000x reference)
//
#include <hip/hip_runtime.h>

typedef __attribute__((ext_vector_type(8))) short bh8;      // 8 bf16 (4 VGPR) MFMA operand
typedef __attribute__((ext_vector_type(4))) float fx4;      // 16x16 MFMA accumulator
typedef __attribute__((ext_vector_type(16))) float fx16;    // 32x32 MFMA accumulator
typedef __attribute__((ext_vector_type(4))) unsigned short us4;
typedef unsigned short u16;

__device__ __forceinline__ u16 f2bf(float x) {
  unsigned u = __float_as_uint(x);
  u += 0x7fffu + ((u >> 16) & 1u);   // RNE
  return (u16)(u >> 16);
}

__device__ __forceinline__ void async16(const void* g, void* l) {
  __builtin_amdgcn_global_load_lds(
      (const __attribute__((address_space(1))) void*)g,
      (__attribute__((address_space(3))) void*)l,
      16, 0, 0);
}

// ---------------------------------------------------------------- convert (weights only now)
__global__ __launch_bounds__(256) void k_convert(
    const float* __restrict__ wq, const float* __restrict__ wk,
    const float* __restrict__ wv, const float* __restrict__ wo,
    u16* __restrict__ dst) {
  size_t gid = (size_t)blockIdx.x * 256 + threadIdx.x;   // group of 4 elements
  size_t e4 = gid * 4;
  const float* src; size_t off;
  if (e4 < 1048576)        { src = wq; off = e4; }
  else if (e4 < 2097152)   { src = wk; off = e4 - 1048576; }
  else if (e4 < 3145728)   { src = wv; off = e4 - 2097152; }
  else                     { src = wo; off = e4 - 3145728; }
  float4 f = *(const float4*)(src + off);
  us4 o; o.x = f2bf(f.x); o.y = f2bf(f.y); o.z = f2bf(f.z); o.w = f2bf(f.w);
  *(us4*)(dst + e4) = o;
}

// ---------------------------------------------------------------- GEMM
// Tile BM x 128, BK=32, 4 waves 2x2. B staged via global_load_lds (bf16 source).
// A: if AF32, reg-staged from fp32 source with T14 split (loads issued post-
// barrier, cvt+ds_write post-compute); LDS layout L(row,c)=G(row,c^(row&3))
// identical to the async path, so the read side is unchanged.
template<int BM>
__device__ __forceinline__ void gemm_stageB(const u16* __restrict__ B, char* lds, int bufbase,
                                            int n0, int kt, int tid) {
  int wb16 = (tid & 0xC0) * 16;
  #pragma unroll
  for (int i = 0; i < 2; ++i) {
    int cl = i * 256 + tid;
    int row = cl >> 2, ch = cl & 3;
    int sch = ch ^ (row & 3);
    const char* gb = (const char*)(B + (size_t)(n0 + row) * 1024 + kt * 32) + sch * 16;
    async16(gb, lds + bufbase + BM * 64 + i * 4096 + wb16);
  }
}

template<int BM>
__device__ __forceinline__ void gemm_stageA16(const u16* __restrict__ A, char* lds, int bufbase,
                                              int m0, int kt, int tid) {
  int wb16 = (tid & 0xC0) * 16;
  #pragma unroll
  for (int i = 0; i < BM / 64; ++i) {
    int cl = i * 256 + tid;
    int row = cl >> 2, ch = cl & 3;
    int sch = ch ^ (row & 3);
    const char* ga = (const char*)(A + (size_t)(m0 + row) * 1024 + kt * 32) + sch * 16;
    async16(ga, lds + bufbase + i * 4096 + wb16);
  }
}

__device__ __forceinline__ void cvt_write16(char* dst, float4 lo, float4 hi) {
  unsigned u0, u1, u2, u3;
  asm("v_cvt_pk_bf16_f32 %0, %1, %2" : "=v"(u0) : "v"(lo.x), "v"(lo.y));
  asm("v_cvt_pk_bf16_f32 %0, %1, %2" : "=v"(u1) : "v"(lo.z), "v"(lo.w));
  asm("v_cvt_pk_bf16_f32 %0, %1, %2" : "=v"(u2) : "v"(hi.x), "v"(hi.y));
  asm("v_cvt_pk_bf16_f32 %0, %1, %2" : "=v"(u3) : "v"(hi.z), "v"(hi.w));
  union { unsigned u[4]; bh8 v; } pu;
  pu.u[0] = u0; pu.u[1] = u1; pu.u[2] = u2; pu.u[3] = u3;
  *(bh8*)dst = pu.v;
}

template<int BM, bool AF32>
__device__ __forceinline__ void gemm_coreT(const void* __restrict__ Ain, const u16* __restrict__ Bw,
                                           const float* __restrict__ bias, void* Cout, int mode,
                                           float scl, char* lds) {
  constexpr int MF = BM / 32;           // m-frags per wave (wave covers BM/2 rows)
  constexpr int BUFSZ = BM * 64 + 8192;
  const float* A32 = (const float*)Ain;
  const u16*   A16 = (const u16*)Ain;
  int tid = threadIdx.x;
  int lane = tid & 63, w = tid >> 6, g = lane >> 4, cc = lane & 15;
  int wr = w >> 1, wc = w & 1;
  int m0 = blockIdx.y * BM, n0 = blockIdx.x * 128;
  int srow = tid >> 2, sch0 = tid & 3;           // this thread's A (row, chunk)
  int adst = srow * 64 + ((sch0 ^ (srow & 3)) * 16);  // swizzled A dest (i=0; +4096 for i=1)
  fx4 acc[MF][4] = {};
  // prologue: stage tile 0 into buf0
  if constexpr (AF32) {
    #pragma unroll
    for (int i = 0; i < BM / 64; ++i) {
      const float* s = A32 + (size_t)(m0 + srow + i * 64) * 1024 + sch0 * 8;
      cvt_write16(lds + i * 4096 + adst, *(const float4*)s, *(const float4*)(s + 4));
    }
  } else {
    gemm_stageA16<BM>(A16, lds, 0, m0, 0, tid);
  }
  gemm_stageB<BM>(Bw, lds, 0, n0, 0, tid);
  for (int kt = 0; kt < 32; ++kt) {
    __syncthreads();   // tile kt ready; all waves done reading buf[(kt+1)&1]
    int bufn = ((kt + 1) & 1) * BUFSZ;
    float4 la[BM / 64][2];
    if (kt + 1 < 32) {
      if constexpr (AF32) {
        #pragma unroll
        for (int i = 0; i < BM / 64; ++i) {       // issue fp32 loads early (T14)
          const float* s = A32 + (size_t)(m0 + srow + i * 64) * 1024 + (kt + 1) * 32 + sch0 * 8;
          la[i][0] = *(const float4*)s;
          la[i][1] = *(const float4*)(s + 4);
        }
      } else {
        gemm_stageA16<BM>(A16, lds, bufn, m0, kt + 1, tid);
      }
      gemm_stageB<BM>(Bw, lds, bufn, n0, kt + 1, tid);
    }
    const char* bA = lds + (kt & 1) * BUFSZ;
    const char* bB = bA + BM * 64;
    bh8 af[MF], bf[4];
    #pragma unroll
    for (int mf = 0; mf < MF; ++mf) {
      int row = wr * (BM / 2) + mf * 16 + cc;
      af[mf] = *(const bh8*)(bA + row * 64 + ((g ^ (row & 3)) * 16));
    }
    #pragma unroll
    for (int nf = 0; nf < 4; ++nf) {
      int row = wc * 64 + nf * 16 + cc;
      bf[nf] = *(const bh8*)(bB + row * 64 + ((g ^ (row & 3)) * 16));
    }
    #pragma unroll
    for (int mf = 0; mf < MF; ++mf)
      #pragma unroll
      for (int nf = 0; nf < 4; ++nf)
        acc[mf][nf] = __builtin_amdgcn_mfma_f32_16x16x32_bf16(af[mf], bf[nf], acc[mf][nf], 0, 0, 0);
    if constexpr (AF32) {
      if (kt + 1 < 32) {                          // cvt + swizzled write, post-compute
        #pragma unroll
        for (int i = 0; i < BM / 64; ++i)
          cvt_write16(lds + bufn + i * 4096 + adst, la[i][0], la[i][1]);
      }
    }
  }
  // epilogue: C row = m0+wr*(BM/2)+mf*16+g*4+r, col = n0+wc*64+nf*16+cc
  #pragma unroll
  for (int mf = 0; mf < MF; ++mf) {
    #pragma unroll
    for (int nf = 0; nf < 4; ++nf) {
      fx4 a = acc[mf][nf];
      int row = m0 + wr * (BM / 2) + mf * 16 + g * 4;
      int col = n0 + wc * 64 + nf * 16 + cc;
      float bv = bias[col];
      if (mode == 0) {                       // bf16 row-major (x scl)
        u16* C = (u16*)Cout;
        #pragma unroll
        for (int r = 0; r < 4; ++r) C[(size_t)(row + r) * 1024 + col] = f2bf((a[r] + bv) * scl);
      } else if (mode == 1) {                // fp32 row-major (final output)
        float* C = (float*)Cout;
        #pragma unroll
        for (int r = 0; r < 4; ++r) C[(size_t)(row + r) * 1024 + col] = (a[r] + bv) * scl;
      } else {                               // transposed bf16: Vt[b*1024+col][s]
        u16* C = (u16*)Cout;
        us4 o;
        #pragma unroll
        for (int r = 0; r < 4; ++r) o[r] = f2bf((a[r] + bv) * scl);
        int bb = row >> 11;
        *(us4*)(C + (size_t)(bb * 1024 + col) * 2048 + (row & 2047)) = o;
      }
    }
  }
}

__global__ __launch_bounds__(256) void k_gemm_qkv(
    const float* __restrict__ q, const float* __restrict__ k, const float* __restrict__ v,
    const u16* __restrict__ wqb, const u16* __restrict__ wkb, const u16* __restrict__ wvb,
    const float* __restrict__ bq, const float* __restrict__ bk, const float* __restrict__ bv,
    u16* __restrict__ Qp, u16* __restrict__ Kp, u16* __restrict__ Vt) {
  __shared__ __align__(16) char lds[32768];
  int z = blockIdx.z;
  const float* A = (z == 0) ? q : (z == 1) ? k : v;
  const u16* B = (z == 0) ? wqb : (z == 1) ? wkb : wvb;
  const float* bias = (z == 0) ? bq : (z == 1) ? bk : bv;
  void* C = (z == 0) ? (void*)Qp : (z == 1) ? (void*)Kp : (void*)Vt;
  float scl = (z == 0) ? 0.18033688f : 1.0f;   // fold 0.125*log2(e) into Q
  gemm_coreT<128, true>(A, B, bias, C, (z == 2) ? 2 : 0, scl, lds);
}

__global__ __launch_bounds__(256) void k_gemm_out(
    const u16* __restrict__ Ob, const u16* __restrict__ wob,
    const float* __restrict__ bo, float* __restrict__ out) {
  __shared__ __align__(16) char lds[24576];    // 2 x (A 4K + B 8K)
  gemm_coreT<64, false>(Ob, wob, bo, out, 1, 1.0f, lds);
}

// ---------------------------------------------------------------- attention (byte-exact R8, verified 52.2us)
// 32x32 MFMA flash attn, KVBLK=128 (16 iters). Block: one (b,h), 128 q-rows
// (4 waves x 32). XCD-aware remap (K/V L2-resident per XCD). Fixed-reference
// softmax with Q pre-scaled by 0.125*log2(e): p = exp2(st) directly.
// K staged with sigma-permuted rows (swap bits 2<->3 of row&15) so the 32x32
// C-layout hands each lane exactly its PV B-fragment k-halves: no cross-lane
// exchange at all. V tile [64 d][256B]; K tile [128 k][128B]; 16B-chunk XOR
// swizzle (row&7) on both; double-buffered, 64 KB LDS.
__global__ __launch_bounds__(256) void k_attn(
    const u16* __restrict__ Qp, const u16* __restrict__ Kp,
    const u16* __restrict__ Vt, u16* __restrict__ O) {
  __shared__ __align__(16) char lds[65536];   // 2 x (K 16K + V 16K)
  int tid = threadIdx.x;
  int lane = tid & 63, w = tid >> 6, ql = lane & 31, hi = lane >> 5;
  // XCD-aware remap (bijective, 512 blocks): each XCD owns 4 whole (b,h)
  int lin = blockIdx.y * 16 + blockIdx.x;
  int xcd = lin & 7, slot = lin >> 3;
  int bh = xcd * 4 + (slot >> 4), qtile = slot & 15;
  int b = bh >> 4, h = bh & 15;
  int q0 = qtile * 128 + w * 32;
  size_t qrow = (size_t)b * 2048 + q0 + ql;
  // Q B-frags (pre-scaled): slot(hi,e) = Q'[q=ql][d = ds*16 + hi*8 + e]
  bh8 qf[4];
  #pragma unroll
  for (int ds = 0; ds < 4; ++ds)
    qf[ds] = *(const bh8*)(Qp + qrow * 1024 + h * 64 + ds * 16 + hi * 8);

  // K staging: dest rows r0 + 32*i (r0 = tid>>3, 0..31), source row sigma(dest):
  // swap bits 2,3 within (row&15); bit4 preserved; chunk swizzle keyed on DEST row.
  int r0 = tid >> 3;
  int gr0 = (r0 & 19) | (((r0 >> 2) & 1) << 3) | (((r0 >> 3) & 1) << 2);  // &19 keeps bits 0,1,4
  int sK = (tid & 7) ^ (r0 & 7);
  const char* gK = (const char*)(Kp + (size_t)(b * 2048 + gr0) * 1024 + h * 64) + sK * 16;
  // V staging: dest rows vr0 + 16*i (vr0 = tid>>4, 0..15), 16 chunks/row (256B)
  int vr0 = tid >> 4;
  int sV = (tid & 15) ^ (vr0 & 7);
  const char* gV = (const char*)(Vt + ((size_t)(b * 1024 + h * 64 + vr0)) * 2048) + sV * 16;
  int wb16 = (tid & 0xC0) * 16;

  // fragment LDS offsets: row&7 == ql&7 for all sub-tiles (strides are mult of 8)
  int x7 = ql & 7;
  int kbase = ql * 128, vbase = ql * 256;
  int kc[4], vc[8];
  #pragma unroll
  for (int ds = 0; ds < 4; ++ds) kc[ds] = ((ds * 2 + hi) ^ x7) * 16;
  #pragma unroll
  for (int ks = 0; ks < 8; ++ks) vc[ks] = ((ks * 2 + hi) ^ x7) * 16;

  float lpart = 0.f;                    // per-lane partial denominator
  fx16 ot[2] = {};                      // O^T: d = dt*32 + 4*hi + (reg&3) + 8*(reg>>2), q = ql
  // prologue stage t=0
  #pragma unroll
  for (int i = 0; i < 4; ++i) {
    async16(gK + i * 65536, lds + i * 4096 + wb16);
    async16(gV + i * 65536, lds + 16384 + i * 4096 + wb16);
  }
  gK += 262144; gV += 256;

  for (int t = 0; t < 16; ++t) {
    __syncthreads();
    if (t + 1 < 16) {
      int bb = ((t + 1) & 1) << 15;
      #pragma unroll
      for (int i = 0; i < 4; ++i) {
        async16(gK + i * 65536, lds + bb + i * 4096 + wb16);
        async16(gV + i * 65536, lds + bb + 16384 + i * 4096 + wb16);
      }
      gK += 262144; gV += 256;
    }
    const char* bK = lds + ((t & 1) << 15);
    const char* bV = bK + 16384;
    // QK^T: st[kk][8m+e] = S[k = kk*32 + 16m + 8hi + e][q=ql]  (sigma-permuted K)
    fx16 st[4] = {};
    #pragma unroll
    for (int kk = 0; kk < 4; ++kk)
      #pragma unroll
      for (int ds = 0; ds < 4; ++ds)
        st[kk] = __builtin_amdgcn_mfma_f32_32x32x16_bf16(
            *(const bh8*)(bK + kk * 4096 + kbase + kc[ds]), qf[ds], st[kk], 0, 0, 0);
    // fixed-reference softmax: p = exp2(st); lane's 8-value groups ARE its PV B-frags
    bh8 Pf[8];
    #pragma unroll
    for (int kk = 0; kk < 4; ++kk) {
      #pragma unroll
      for (int m = 0; m < 2; ++m) {
        float p[8];
        #pragma unroll
        for (int e = 0; e < 8; ++e) p[e] = __builtin_amdgcn_exp2f(st[kk][8 * m + e]);
        lpart += ((p[0] + p[1]) + (p[2] + p[3])) + ((p[4] + p[5]) + (p[6] + p[7]));
        unsigned u0, u1, u2, u3;
        asm("v_cvt_pk_bf16_f32 %0, %1, %2" : "=v"(u0) : "v"(p[0]), "v"(p[1]));
        asm("v_cvt_pk_bf16_f32 %0, %1, %2" : "=v"(u1) : "v"(p[2]), "v"(p[3]));
        asm("v_cvt_pk_bf16_f32 %0, %1, %2" : "=v"(u2) : "v"(p[4]), "v"(p[5]));
        asm("v_cvt_pk_bf16_f32 %0, %1, %2" : "=v"(u3) : "v"(p[6]), "v"(p[7]));
        union { unsigned u[4]; bh8 v; } pu;
        pu.u[0] = u0; pu.u[1] = u1; pu.u[2] = u2; pu.u[3] = u3;
        Pf[kk * 2 + m] = pu.v;
      }
    }
    // O^T += V^T * P^T  (2 d-tiles x 8 K=16 slices)
    #pragma unroll
    for (int dt = 0; dt < 2; ++dt)
      #pragma unroll
      for (int ks = 0; ks < 8; ++ks)
        ot[dt] = __builtin_amdgcn_mfma_f32_32x32x16_bf16(
            *(const bh8*)(bV + dt * 8192 + vbase + vc[ks]), Pf[ks], ot[dt], 0, 0, 0);
  }
  // denominator: lane pair (ql, ql+32) sums to the full row
  float lsum = lpart + __shfl_xor(lpart, 32);
  float inv = 1.f / lsum;
  #pragma unroll
  for (int dt = 0; dt < 2; ++dt)
    #pragma unroll
    for (int j = 0; j < 4; ++j) {
      us4 o4;
      #pragma unroll
      for (int i = 0; i < 4; ++i) o4[i] = f2bf(ot[dt][4 * j + i] * inv);
      *(us4*)(O + qrow * 1024 + h * 64 + dt * 32 + j * 8 + hi * 4) = o4;
    }
}

// ---------------------------------------------------------------- launch
extern "C" void kernel_launch(void* const* d_in, const int* in_sizes, int n_in,
                              void* d_out, int out_size, void* d_ws, size_t ws_size,
                              hipStream_t stream) {
  const float* q  = (const float*)d_in[0];
  const float* k  = (const float*)d_in[1];
  const float* v  = (const float*)d_in[2];
  const float* Wq = (const float*)d_in[3];
  const float* bq = (const float*)d_in[4];
  const float* Wk = (const float*)d_in[5];
  const float* bk = (const float*)d_in[6];
  const float* Wv = (const float*)d_in[7];
  const float* bv = (const float*)d_in[8];
  const float* Wo = (const float*)d_in[9];
  const float* bo = (const float*)d_in[10];
  u16* ws  = (u16*)d_ws;
  u16* qb  = ws;               // [4096,1024] bf16 (now only used as attn output Ob)
  u16* kb  = qb + 4194304;     // (unused)
  u16* vb  = kb + 4194304;     // (unused)
  u16* wqb = vb + 4194304;     // [1024,1024] bf16 each
  u16* wkb = wqb + 1048576;
  u16* wvb = wkb + 1048576;
  u16* wob = wvb + 1048576;
  u16* Qp  = wob + 1048576;    // [4096,1024] bf16 (pre-scaled by 0.125*log2e)
  u16* Kp  = Qp + 4194304;
  u16* Vt  = Kp + 4194304;     // [2048,2048] bf16 (V transposed per batch)
  u16* Ob  = qb;               // attention output

  k_convert<<<dim3(4096), 256, 0, stream>>>(Wq, Wk, Wv, Wo, wqb);
  k_gemm_qkv<<<dim3(8, 32, 3), 256, 0, stream>>>(q, k, v, wqb, wkb, wvb, bq, bk, bv, Qp, Kp, Vt);
  k_attn<<<dim3(16, 32), 256, 0, stream>>>(Qp, Kp, Vt, Ob);
  k_gemm_out<<<dim3(8, 64), 256, 0, stream>>>(Ob, wob, bo, (float*)d_out);
}

// Round 12
// 111.983 us; speedup vs baseline: 1.1880x; 1.1880x over previous
//
#include <hip/hip_runtime.h>

typedef __attribute__((ext_vector_type(8))) short bh8;      // 8 bf16 (4 VGPR) MFMA operand
typedef __attribute__((ext_vector_type(4))) float fx4;      // 16x16 MFMA accumulator
typedef __attribute__((ext_vector_type(16))) float fx16;    // 32x32 MFMA accumulator
typedef __attribute__((ext_vector_type(4))) unsigned short us4;
typedef unsigned short u16;

__device__ __forceinline__ u16 f2bf(float x) {
  unsigned u = __float_as_uint(x);
  u += 0x7fffu + ((u >> 16) & 1u);   // RNE
  return (u16)(u >> 16);
}

__device__ __forceinline__ void async16(const void* g, void* l) {
  __builtin_amdgcn_global_load_lds(
      (const __attribute__((address_space(1))) void*)g,
      (__attribute__((address_space(3))) void*)l,
      16, 0, 0);
}

// ---------------------------------------------------------------- convert (weights only)
__global__ __launch_bounds__(256) void k_convert(
    const float* __restrict__ wq, const float* __restrict__ wk,
    const float* __restrict__ wv, const float* __restrict__ wo,
    u16* __restrict__ dst) {
  size_t gid = (size_t)blockIdx.x * 256 + threadIdx.x;   // group of 4 elements
  size_t e4 = gid * 4;
  const float* src; size_t off;
  if (e4 < 1048576)        { src = wq; off = e4; }
  else if (e4 < 2097152)   { src = wk; off = e4 - 1048576; }
  else if (e4 < 3145728)   { src = wv; off = e4 - 2097152; }
  else                     { src = wo; off = e4 - 3145728; }
  float4 f = *(const float4*)(src + off);
  us4 o; o.x = f2bf(f.x); o.y = f2bf(f.y); o.z = f2bf(f.z); o.w = f2bf(f.w);
  *(us4*)(dst + e4) = o;
}

// ---------------------------------------------------------------- GEMM
// Tile BM x 128, BK=32, 4 waves 2x2. B staged via global_load_lds (bf16 source).
// A: if AF32, reg-staged from fp32 source with T14 split (loads issued post-
// barrier, cvt+ds_write post-compute); LDS layout L(row,c)=G(row,c^(row&3))
// identical to the async path, so the read side is unchanged.
template<int BM>
__device__ __forceinline__ void gemm_stageB(const u16* __restrict__ B, char* lds, int bufbase,
                                            int n0, int kt, int tid) {
  int wb16 = (tid & 0xC0) * 16;
  #pragma unroll
  for (int i = 0; i < 2; ++i) {
    int cl = i * 256 + tid;
    int row = cl >> 2, ch = cl & 3;
    int sch = ch ^ (row & 3);
    const char* gb = (const char*)(B + (size_t)(n0 + row) * 1024 + kt * 32) + sch * 16;
    async16(gb, lds + bufbase + BM * 64 + i * 4096 + wb16);
  }
}

template<int BM>
__device__ __forceinline__ void gemm_stageA16(const u16* __restrict__ A, char* lds, int bufbase,
                                              int m0, int kt, int tid) {
  int wb16 = (tid & 0xC0) * 16;
  #pragma unroll
  for (int i = 0; i < BM / 64; ++i) {
    int cl = i * 256 + tid;
    int row = cl >> 2, ch = cl & 3;
    int sch = ch ^ (row & 3);
    const char* ga = (const char*)(A + (size_t)(m0 + row) * 1024 + kt * 32) + sch * 16;
    async16(ga, lds + bufbase + i * 4096 + wb16);
  }
}

__device__ __forceinline__ void cvt_write16(char* dst, float4 lo, float4 hi) {
  unsigned u0, u1, u2, u3;
  asm("v_cvt_pk_bf16_f32 %0, %1, %2" : "=v"(u0) : "v"(lo.x), "v"(lo.y));
  asm("v_cvt_pk_bf16_f32 %0, %1, %2" : "=v"(u1) : "v"(lo.z), "v"(lo.w));
  asm("v_cvt_pk_bf16_f32 %0, %1, %2" : "=v"(u2) : "v"(hi.x), "v"(hi.y));
  asm("v_cvt_pk_bf16_f32 %0, %1, %2" : "=v"(u3) : "v"(hi.z), "v"(hi.w));
  union { unsigned u[4]; bh8 v; } pu;
  pu.u[0] = u0; pu.u[1] = u1; pu.u[2] = u2; pu.u[3] = u3;
  *(bh8*)dst = pu.v;
}

template<int BM, bool AF32>
__device__ __forceinline__ void gemm_coreT(const void* __restrict__ Ain, const u16* __restrict__ Bw,
                                           const float* __restrict__ bias, void* Cout, int mode,
                                           float scl, char* lds, int m0, int n0) {
  constexpr int MF = BM / 32;           // m-frags per wave (wave covers BM/2 rows)
  constexpr int BUFSZ = BM * 64 + 8192;
  const float* A32 = (const float*)Ain;
  const u16*   A16 = (const u16*)Ain;
  int tid = threadIdx.x;
  int lane = tid & 63, w = tid >> 6, g = lane >> 4, cc = lane & 15;
  int wr = w >> 1, wc = w & 1;
  int srow = tid >> 2, sch0 = tid & 3;           // this thread's A (row, chunk)
  int adst = srow * 64 + ((sch0 ^ (srow & 3)) * 16);  // swizzled A dest (i=0; +4096 for i=1)
  fx4 acc[MF][4] = {};
  // prologue: stage tile 0 into buf0
  if constexpr (AF32) {
    #pragma unroll
    for (int i = 0; i < BM / 64; ++i) {
      const float* s = A32 + (size_t)(m0 + srow + i * 64) * 1024 + sch0 * 8;
      cvt_write16(lds + i * 4096 + adst, *(const float4*)s, *(const float4*)(s + 4));
    }
  } else {
    gemm_stageA16<BM>(A16, lds, 0, m0, 0, tid);
  }
  gemm_stageB<BM>(Bw, lds, 0, n0, 0, tid);
  for (int kt = 0; kt < 32; ++kt) {
    __syncthreads();   // tile kt ready; all waves done reading buf[(kt+1)&1]
    int bufn = ((kt + 1) & 1) * BUFSZ;
    float4 la[BM / 64][2];
    if (kt + 1 < 32) {
      if constexpr (AF32) {
        #pragma unroll
        for (int i = 0; i < BM / 64; ++i) {       // issue fp32 loads early (T14)
          const float* s = A32 + (size_t)(m0 + srow + i * 64) * 1024 + (kt + 1) * 32 + sch0 * 8;
          la[i][0] = *(const float4*)s;
          la[i][1] = *(const float4*)(s + 4);
        }
      } else {
        gemm_stageA16<BM>(A16, lds, bufn, m0, kt + 1, tid);
      }
      gemm_stageB<BM>(Bw, lds, bufn, n0, kt + 1, tid);
    }
    const char* bA = lds + (kt & 1) * BUFSZ;
    const char* bB = bA + BM * 64;
    bh8 af[MF], bf[4];
    #pragma unroll
    for (int mf = 0; mf < MF; ++mf) {
      int row = wr * (BM / 2) + mf * 16 + cc;
      af[mf] = *(const bh8*)(bA + row * 64 + ((g ^ (row & 3)) * 16));
    }
    #pragma unroll
    for (int nf = 0; nf < 4; ++nf) {
      int row = wc * 64 + nf * 16 + cc;
      bf[nf] = *(const bh8*)(bB + row * 64 + ((g ^ (row & 3)) * 16));
    }
    #pragma unroll
    for (int mf = 0; mf < MF; ++mf)
      #pragma unroll
      for (int nf = 0; nf < 4; ++nf)
        acc[mf][nf] = __builtin_amdgcn_mfma_f32_16x16x32_bf16(af[mf], bf[nf], acc[mf][nf], 0, 0, 0);
    if constexpr (AF32) {
      if (kt + 1 < 32) {                          // cvt + swizzled write, post-compute
        #pragma unroll
        for (int i = 0; i < BM / 64; ++i)
          cvt_write16(lds + bufn + i * 4096 + adst, la[i][0], la[i][1]);
      }
    }
  }
  // epilogue: C row = m0+wr*(BM/2)+mf*16+g*4+r, col = n0+wc*64+nf*16+cc
  #pragma unroll
  for (int mf = 0; mf < MF; ++mf) {
    #pragma unroll
    for (int nf = 0; nf < 4; ++nf) {
      fx4 a = acc[mf][nf];
      int row = m0 + wr * (BM / 2) + mf * 16 + g * 4;
      int col = n0 + wc * 64 + nf * 16 + cc;
      float bv = bias[col];
      if (mode == 0) {                       // bf16 row-major (x scl)
        u16* C = (u16*)Cout;
        #pragma unroll
        for (int r = 0; r < 4; ++r) C[(size_t)(row + r) * 1024 + col] = f2bf((a[r] + bv) * scl);
      } else if (mode == 1) {                // fp32 row-major (final output)
        float* C = (float*)Cout;
        #pragma unroll
        for (int r = 0; r < 4; ++r) C[(size_t)(row + r) * 1024 + col] = (a[r] + bv) * scl;
      } else {                               // transposed bf16: Vt[b*1024+col][s]
        u16* C = (u16*)Cout;
        us4 o;
        #pragma unroll
        for (int r = 0; r < 4; ++r) o[r] = f2bf((a[r] + bv) * scl);
        int bb = row >> 11;
        *(us4*)(C + (size_t)(bb * 1024 + col) * 2048 + (row & 2047)) = o;
      }
    }
  }
}

// panel->XCD swizzle: all 8 n-blocks of one A-panel get dispatch indices == c (mod 8)
// -> same XCD -> A panel read once from HBM, 7 L2 hits. (Mechanism HW-validated in
// this session: attn remap cut FETCH 69.7->12.3 MB.)
__global__ __launch_bounds__(256) void k_gemm_qkv(
    const float* __restrict__ q, const float* __restrict__ k, const float* __restrict__ v,
    const u16* __restrict__ wqb, const u16* __restrict__ wkb, const u16* __restrict__ wvb,
    const float* __restrict__ bq, const float* __restrict__ bk, const float* __restrict__ bv,
    u16* __restrict__ Qp, u16* __restrict__ Kp, u16* __restrict__ Vt) {
  __shared__ __align__(16) char lds[32768];
  int lin = blockIdx.x + 8 * blockIdx.y + 256 * blockIdx.z;   // 768 blocks
  int c = lin & 7, j = lin >> 3;
  int p = c * 12 + (j >> 3), x = j & 7;    // bijective: p in 0..95, x in 0..7
  int z = p >> 5, y = p & 31;
  const float* A = (z == 0) ? q : (z == 1) ? k : v;
  const u16* B = (z == 0) ? wqb : (z == 1) ? wkb : wvb;
  const float* bias = (z == 0) ? bq : (z == 1) ? bk : bv;
  void* C = (z == 0) ? (void*)Qp : (z == 1) ? (void*)Kp : (void*)Vt;
  float scl = (z == 0) ? 0.18033688f : 1.0f;   // fold 0.125*log2(e) into Q
  gemm_coreT<128, true>(A, B, bias, C, (z == 2) ? 2 : 0, scl, lds, y * 128, x * 128);
}

__global__ __launch_bounds__(256) void k_gemm_out(
    const u16* __restrict__ Ob, const u16* __restrict__ wob,
    const float* __restrict__ bo, float* __restrict__ out) {
  __shared__ __align__(16) char lds[24576];    // 2 x (A 4K + B 8K)
  int lin = blockIdx.x + 8 * blockIdx.y;       // 512 blocks
  int c = lin & 7, j = lin >> 3;
  int p = c * 8 + (j >> 3), x = j & 7;         // bijective: p in 0..63
  gemm_coreT<64, false>(Ob, wob, bo, out, 1, 1.0f, lds, p * 64, x * 128);
}

// ---------------------------------------------------------------- attention (byte-exact R8, verified 52.2us)
// 32x32 MFMA flash attn, KVBLK=128 (16 iters). Block: one (b,h), 128 q-rows
// (4 waves x 32). XCD-aware remap (K/V L2-resident per XCD). Fixed-reference
// softmax with Q pre-scaled by 0.125*log2(e): p = exp2(st) directly.
// K staged with sigma-permuted rows (swap bits 2<->3 of row&15) so the 32x32
// C-layout hands each lane exactly its PV B-fragment k-halves: no cross-lane
// exchange at all. V tile [64 d][256B]; K tile [128 k][128B]; 16B-chunk XOR
// swizzle (row&7) on both; double-buffered, 64 KB LDS.
__global__ __launch_bounds__(256) void k_attn(
    const u16* __restrict__ Qp, const u16* __restrict__ Kp,
    const u16* __restrict__ Vt, u16* __restrict__ O) {
  __shared__ __align__(16) char lds[65536];   // 2 x (K 16K + V 16K)
  int tid = threadIdx.x;
  int lane = tid & 63, w = tid >> 6, ql = lane & 31, hi = lane >> 5;
  // XCD-aware remap (bijective, 512 blocks): each XCD owns 4 whole (b,h)
  int lin = blockIdx.y * 16 + blockIdx.x;
  int xcd = lin & 7, slot = lin >> 3;
  int bh = xcd * 4 + (slot >> 4), qtile = slot & 15;
  int b = bh >> 4, h = bh & 15;
  int q0 = qtile * 128 + w * 32;
  size_t qrow = (size_t)b * 2048 + q0 + ql;
  // Q B-frags (pre-scaled): slot(hi,e) = Q'[q=ql][d = ds*16 + hi*8 + e]
  bh8 qf[4];
  #pragma unroll
  for (int ds = 0; ds < 4; ++ds)
    qf[ds] = *(const bh8*)(Qp + qrow * 1024 + h * 64 + ds * 16 + hi * 8);

  // K staging: dest rows r0 + 32*i (r0 = tid>>3, 0..31), source row sigma(dest):
  // swap bits 2,3 within (row&15); bit4 preserved; chunk swizzle keyed on DEST row.
  int r0 = tid >> 3;
  int gr0 = (r0 & 19) | (((r0 >> 2) & 1) << 3) | (((r0 >> 3) & 1) << 2);  // &19 keeps bits 0,1,4
  int sK = (tid & 7) ^ (r0 & 7);
  const char* gK = (const char*)(Kp + (size_t)(b * 2048 + gr0) * 1024 + h * 64) + sK * 16;
  // V staging: dest rows vr0 + 16*i (vr0 = tid>>4, 0..15), 16 chunks/row (256B)
  int vr0 = tid >> 4;
  int sV = (tid & 15) ^ (vr0 & 7);
  const char* gV = (const char*)(Vt + ((size_t)(b * 1024 + h * 64 + vr0)) * 2048) + sV * 16;
  int wb16 = (tid & 0xC0) * 16;

  // fragment LDS offsets: row&7 == ql&7 for all sub-tiles (strides are mult of 8)
  int x7 = ql & 7;
  int kbase = ql * 128, vbase = ql * 256;
  int kc[4], vc[8];
  #pragma unroll
  for (int ds = 0; ds < 4; ++ds) kc[ds] = ((ds * 2 + hi) ^ x7) * 16;
  #pragma unroll
  for (int ks = 0; ks < 8; ++ks) vc[ks] = ((ks * 2 + hi) ^ x7) * 16;

  float lpart = 0.f;                    // per-lane partial denominator
  fx16 ot[2] = {};                      // O^T: d = dt*32 + 4*hi + (reg&3) + 8*(reg>>2), q = ql
  // prologue stage t=0
  #pragma unroll
  for (int i = 0; i < 4; ++i) {
    async16(gK + i * 65536, lds + i * 4096 + wb16);
    async16(gV + i * 65536, lds + 16384 + i * 4096 + wb16);
  }
  gK += 262144; gV += 256;

  for (int t = 0; t < 16; ++t) {
    __syncthreads();
    if (t + 1 < 16) {
      int bb = ((t + 1) & 1) << 15;
      #pragma unroll
      for (int i = 0; i < 4; ++i) {
        async16(gK + i * 65536, lds + bb + i * 4096 + wb16);
        async16(gV + i * 65536, lds + bb + 16384 + i * 4096 + wb16);
      }
      gK += 262144; gV += 256;
    }
    const char* bK = lds + ((t & 1) << 15);
    const char* bV = bK + 16384;
    // QK^T: st[kk][8m+e] = S[k = kk*32 + 16m + 8hi + e][q=ql]  (sigma-permuted K)
    fx16 st[4] = {};
    #pragma unroll
    for (int kk = 0; kk < 4; ++kk)
      #pragma unroll
      for (int ds = 0; ds < 4; ++ds)
        st[kk] = __builtin_amdgcn_mfma_f32_32x32x16_bf16(
            *(const bh8*)(bK + kk * 4096 + kbase + kc[ds]), qf[ds], st[kk], 0, 0, 0);
    // fixed-reference softmax: p = exp2(st); lane's 8-value groups ARE its PV B-frags
    bh8 Pf[8];
    #pragma unroll
    for (int kk = 0; kk < 4; ++kk) {
      #pragma unroll
      for (int m = 0; m < 2; ++m) {
        float p[8];
        #pragma unroll
        for (int e = 0; e < 8; ++e) p[e] = __builtin_amdgcn_exp2f(st[kk][8 * m + e]);
        lpart += ((p[0] + p[1]) + (p[2] + p[3])) + ((p[4] + p[5]) + (p[6] + p[7]));
        unsigned u0, u1, u2, u3;
        asm("v_cvt_pk_bf16_f32 %0, %1, %2" : "=v"(u0) : "v"(p[0]), "v"(p[1]));
        asm("v_cvt_pk_bf16_f32 %0, %1, %2" : "=v"(u1) : "v"(p[2]), "v"(p[3]));
        asm("v_cvt_pk_bf16_f32 %0, %1, %2" : "=v"(u2) : "v"(p[4]), "v"(p[5]));
        asm("v_cvt_pk_bf16_f32 %0, %1, %2" : "=v"(u3) : "v"(p[6]), "v"(p[7]));
        union { unsigned u[4]; bh8 v; } pu;
        pu.u[0] = u0; pu.u[1] = u1; pu.u[2] = u2; pu.u[3] = u3;
        Pf[kk * 2 + m] = pu.v;
      }
    }
    // O^T += V^T * P^T  (2 d-tiles x 8 K=16 slices)
    #pragma unroll
    for (int dt = 0; dt < 2; ++dt)
      #pragma unroll
      for (int ks = 0; ks < 8; ++ks)
        ot[dt] = __builtin_amdgcn_mfma_f32_32x32x16_bf16(
            *(const bh8*)(bV + dt * 8192 + vbase + vc[ks]), Pf[ks], ot[dt], 0, 0, 0);
  }
  // denominator: lane pair (ql, ql+32) sums to the full row
  float lsum = lpart + __shfl_xor(lpart, 32);
  float inv = 1.f / lsum;
  #pragma unroll
  for (int dt = 0; dt < 2; ++dt)
    #pragma unroll
    for (int j = 0; j < 4; ++j) {
      us4 o4;
      #pragma unroll
      for (int i = 0; i < 4; ++i) o4[i] = f2bf(ot[dt][4 * j + i] * inv);
      *(us4*)(O + qrow * 1024 + h * 64 + dt * 32 + j * 8 + hi * 4) = o4;
    }
}

// ---------------------------------------------------------------- launch
extern "C" void kernel_launch(void* const* d_in, const int* in_sizes, int n_in,
                              void* d_out, int out_size, void* d_ws, size_t ws_size,
                              hipStream_t stream) {
  const float* q  = (const float*)d_in[0];
  const float* k  = (const float*)d_in[1];
  const float* v  = (const float*)d_in[2];
  const float* Wq = (const float*)d_in[3];
  const float* bq = (const float*)d_in[4];
  const float* Wk = (const float*)d_in[5];
  const float* bk = (const float*)d_in[6];
  const float* Wv = (const float*)d_in[7];
  const float* bv = (const float*)d_in[8];
  const float* Wo = (const float*)d_in[9];
  const float* bo = (const float*)d_in[10];
  u16* ws  = (u16*)d_ws;
  u16* qb  = ws;               // [4096,1024] bf16 (attn output Ob)
  u16* kb  = qb + 4194304;     // (unused)
  u16* vb  = kb + 4194304;     // (unused)
  u16* wqb = vb + 4194304;     // [1024,1024] bf16 each
  u16* wkb = wqb + 1048576;
  u16* wvb = wkb + 1048576;
  u16* wob = wvb + 1048576;
  u16* Qp  = wob + 1048576;    // [4096,1024] bf16 (pre-scaled by 0.125*log2e)
  u16* Kp  = Qp + 4194304;
  u16* Vt  = Kp + 4194304;     // [2048,2048] bf16 (V transposed per batch)
  u16* Ob  = qb;               // attention output

  k_convert<<<dim3(4096), 256, 0, stream>>>(Wq, Wk, Wv, Wo, wqb);
  k_gemm_qkv<<<dim3(8, 32, 3), 256, 0, stream>>>(q, k, v, wqb, wkb, wvb, bq, bk, bv, Qp, Kp, Vt);
  k_attn<<<dim3(16, 32), 256, 0, stream>>>(Qp, Kp, Vt, Ob);
  k_gemm_out<<<dim3(8, 64), 256, 0, stream>>>(Ob, wob, bo, (float*)d_out);
}